// Round 6
// baseline (390.664 us; speedup 1.0000x reference)
//
#include <hip/hip_runtime.h>
#include <math.h>

#define NB    64        // graphs
#define NPER  1024      // nodes per graph
#define NTOT  65536     // total nodes
#define ETOT  1048576   // edges
#define FEAT  64
#define HID   128
#define KSEL  10
#define MAXDEG 64       // CSR slot capacity per node (max in-degree ~40)

// Structure (agg commuted before the weight multiply):
//   a   = agg(h)            agg_k   : LDS-staged, dinv folded into staging + epilogue
//   h'  = relu(a W + b)     gemm_k  : 128x128 tile, fused epilogue (bias/relu/maxpool/f*gproj)
// Layouts:
//   feature buffers : chunk-major  C[c][v][16]
//   col16           : slot-major   col16[i][v] = local (10-bit) neighbor index, u16

// ---------------- CSR build (slot-major, u16 local index) ----------------
__global__ __launch_bounds__(256) void csr_k(const int* __restrict__ src,
                                             const int* __restrict__ dst,
                                             int* __restrict__ cnt,
                                             unsigned short* __restrict__ col16) {
    int e = blockIdx.x * 256 + threadIdx.x;
    if (e >= ETOT) return;
    int d = dst[e];
    int s = src[e];
    int pos = atomicAdd(&cnt[d], 1);
    col16[(size_t)pos * NTOT + d] = (unsigned short)(s & (NPER - 1));
}

__global__ __launch_bounds__(256) void dinv_k(const int* __restrict__ cnt,
                                              float* __restrict__ dinv) {
    int v = blockIdx.x * 256 + threadIdx.x;
    dinv[v] = rsqrtf((float)cnt[v] + 1.0f);
}

// f_v = dinv_v * (dinv_v + sum_s dinv_s)   (agg of a per-graph-constant vector)
__global__ __launch_bounds__(256) void fsum_k(const unsigned short* __restrict__ col16,
                                              const int* __restrict__ cnt,
                                              const float* __restrict__ dinv,
                                              float* __restrict__ f) {
    int v = blockIdx.x * 256 + threadIdx.x;
    int gbase = v & ~(NPER - 1);
    int n = cnt[v];
    float dv = dinv[v];
    float acc = dv;
    const unsigned short* ip = col16 + v;
    for (int i = 0; i < n; ++i) acc += dinv[gbase + ip[(size_t)i * NTOT]];
    f[v] = dv * acc;
}

// ---------------- LDS-staged aggregation: out = dinv_v * sum(dinv.*in over N(v)+self)
// block = (graph g, chunk c); 1024 threads, 4 lanes per node. Input either
// chunk-major H or row-major x (64-wide).
__global__ __launch_bounds__(1024) void agg_k(const float* __restrict__ H,
                                              const float* __restrict__ x,
                                              const unsigned short* __restrict__ col16,
                                              const int* __restrict__ cnt,
                                              const float* __restrict__ dinv,
                                              float* __restrict__ out,
                                              int cshift) {
    __shared__ float4 sy4[4096];   // 64 KB
    int t = threadIdx.x;
    int g = blockIdx.x >> cshift;
    int c = blockIdx.x & ((1 << cshift) - 1);
    int gbase = g << 10;

#pragma unroll
    for (int j = 0; j < 4; ++j) {
        int fl = j * 1024 + t;
        int v = fl >> 2, q = fl & 3;
        float dvv = dinv[gbase + v];
        float4 z;
        if (x) z = *(const float4*)&x[(size_t)(gbase + v) * FEAT + c * 16 + q * 4];
        else   z = *(const float4*)&H[((size_t)c * NTOT + gbase + v) * 16 + q * 4];
        z.x *= dvv; z.y *= dvv; z.z *= dvv; z.w *= dvv;
        sy4[fl] = z;
    }
    __syncthreads();

    int f4 = t & 3;
    int vl = t >> 2;                        // 0..255

#pragma unroll 1
    for (int pass = 0; pass < 4; ++pass) {
        int v = pass * 256 + vl;
        int gv = gbase + v;
        int n = cnt[gv];
        float dv = rsqrtf((float)n + 1.0f);
        const unsigned short* ip = col16 + gv;
        float4 acc = sy4[v * 4 + f4];       // self term (already dinv-scaled)
        int i = 0;
        for (; i + 2 <= n; i += 2) {
            int a = ip[(size_t)i * NTOT];
            int b = ip[(size_t)(i + 1) * NTOT];
            float4 ya = sy4[a * 4 + f4];
            float4 yb = sy4[b * 4 + f4];
            acc.x += ya.x + yb.x;
            acc.y += ya.y + yb.y;
            acc.z += ya.z + yb.z;
            acc.w += ya.w + yb.w;
        }
        if (i < n) {
            float4 ya = sy4[(int)ip[(size_t)i * NTOT] * 4 + f4];
            acc.x += ya.x; acc.y += ya.y; acc.z += ya.z; acc.w += ya.w;
        }
        acc.x *= dv; acc.y *= dv; acc.z *= dv; acc.w *= dv;
        *(float4*)&out[((size_t)c * NTOT + gv) * 16 + f4 * 4] = acc;
    }
}

// ---------------- fp32 GEMM 128x128 tile, 8x8 micro-tile, fused epilogue ----------
// out = relu(A@W + bias (+ f[row]*gproj[g])) ; optional per-graph col-max -> part
__global__ __launch_bounds__(256, 4) void gemm_k(const float* __restrict__ A,
                                                 const float* __restrict__ W,
                                                 const float* __restrict__ bias,
                                                 float* __restrict__ out,
                                                 int K,
                                                 const float* __restrict__ fvec,
                                                 const float* __restrict__ gproj,
                                                 float* __restrict__ part) {
    __shared__ float At[32][140];   // [k][row], stride 140: 16B-aligned, <=2-way conflicts
    __shared__ float Wt[32][128];   // [k][col]
    int t = threadIdx.x;
    int row0 = blockIdx.x * 128;
    int tx = t & 15;                // col group: cols tx*8..+7
    int ty = t >> 4;                // row group: rows ty*8..+7

    float acc[8][8];
#pragma unroll
    for (int i = 0; i < 8; ++i)
#pragma unroll
        for (int j = 0; j < 8; ++j) acc[i][j] = 0.f;

    for (int kt = 0; kt < K; kt += 32) {
        {   // stage A (chunk-major input): 2 chunks x 128 rows x 16 k, transposed
            int q = t & 3, r0 = t >> 2;     // r0: 0..63
#pragma unroll
            for (int half = 0; half < 2; ++half) {
                int cc = (kt >> 4) + half;
#pragma unroll
                for (int p = 0; p < 2; ++p) {
                    int r = r0 + p * 64;
                    float4 v4 = *(const float4*)&A[((size_t)cc * NTOT + row0 + r) * 16 + q * 4];
                    At[half * 16 + q * 4 + 0][r] = v4.x;
                    At[half * 16 + q * 4 + 1][r] = v4.y;
                    At[half * 16 + q * 4 + 2][r] = v4.z;
                    At[half * 16 + q * 4 + 3][r] = v4.w;
                }
            }
        }
        {   // stage W: 32 k x 128 cols
            int c4 = (t & 31) * 4, kr = t >> 5;
#pragma unroll
            for (int p = 0; p < 4; ++p) {
                int k = kr + p * 8;
                *(float4*)&Wt[k][c4] = *(const float4*)&W[(size_t)(kt + k) * 128 + c4];
            }
        }
        __syncthreads();
#pragma unroll
        for (int k = 0; k < 32; ++k) {
            float4 a0 = *(const float4*)&At[k][ty * 8];
            float4 a1 = *(const float4*)&At[k][ty * 8 + 4];
            float4 w0 = *(const float4*)&Wt[k][tx * 8];
            float4 w1 = *(const float4*)&Wt[k][tx * 8 + 4];
            float a[8] = {a0.x, a0.y, a0.z, a0.w, a1.x, a1.y, a1.z, a1.w};
            float w[8] = {w0.x, w0.y, w0.z, w0.w, w1.x, w1.y, w1.z, w1.w};
#pragma unroll
            for (int i = 0; i < 8; ++i)
#pragma unroll
                for (int j = 0; j < 8; ++j) acc[i][j] += a[i] * w[j];
        }
        __syncthreads();
    }

    int g = row0 >> 10;
    float b[8];
#pragma unroll
    for (int j = 0; j < 8; ++j) b[j] = bias[tx * 8 + j];
    float gp[8], fr[8];
    if (fvec) {
#pragma unroll
        for (int j = 0; j < 8; ++j) gp[j] = gproj[(size_t)g * 128 + tx * 8 + j];
#pragma unroll
        for (int i = 0; i < 8; ++i) fr[i] = fvec[row0 + ty * 8 + i];
    }
    float m[8];
#pragma unroll
    for (int j = 0; j < 8; ++j) m[j] = 0.f;   // relu floor

    int cc = tx >> 1, off = (tx & 1) * 8;
#pragma unroll
    for (int i = 0; i < 8; ++i) {
        int r = row0 + ty * 8 + i;
        float o[8];
#pragma unroll
        for (int j = 0; j < 8; ++j) {
            float v = acc[i][j] + b[j];
            if (fvec) v += fr[i] * gp[j];
            v = fmaxf(v, 0.f);
            o[j] = v;
            if (part) m[j] = fmaxf(m[j], v);
        }
        float* op = &out[((size_t)cc * NTOT + r) * 16 + off];
        *(float4*)op       = make_float4(o[0], o[1], o[2], o[3]);
        *(float4*)(op + 4) = make_float4(o[4], o[5], o[6], o[7]);
    }

    if (part) {   // reduce col-max across the 16 row-groups, then atomicMax
        float* sm = &At[0][0];   // 16*128 floats, fits
        __syncthreads();
#pragma unroll
        for (int j = 0; j < 8; ++j) sm[ty * 128 + tx * 8 + j] = m[j];
        __syncthreads();
        for (int s = 8; s >= 1; s >>= 1) {
            if (ty < s) {
#pragma unroll
                for (int j = 0; j < 8; ++j) {
                    int idx = ty * 128 + tx * 8 + j;
                    sm[idx] = fmaxf(sm[idx], sm[(ty + s) * 128 + tx * 8 + j]);
                }
            }
            __syncthreads();
        }
        if (ty == 0) {
            int* pp = (int*)&part[(size_t)g * 128 + tx * 8];
#pragma unroll
            for (int j = 0; j < 8; ++j) atomicMax(pp + j, __float_as_int(sm[tx * 8 + j]));
        }
    }
}

// ---------------- glob = maxpool@Wf + bf ; gproj = glob @ W2[128:256,:] --------------
__global__ __launch_bounds__(128) void glob_k(const float* __restrict__ part,
                                              const float* __restrict__ Wf,
                                              const float* __restrict__ bf,
                                              const float* __restrict__ W2,
                                              float* __restrict__ gproj) {
    __shared__ float mp[128];
    __shared__ float gl[128];
    int g = blockIdx.x, t = threadIdx.x;
    mp[t] = part[(size_t)g * 128 + t];
    __syncthreads();
    float acc = bf[t];
    for (int k = 0; k < 128; ++k) acc += mp[k] * Wf[(size_t)k * 128 + t];
    gl[t] = acc;
    __syncthreads();
    float acc2 = 0.f;
    for (int k = 0; k < 128; ++k) acc2 += gl[k] * W2[(size_t)(128 + k) * 128 + t];
    gproj[(size_t)g * 128 + t] = acc2;
}

// ---------------- z[v] = dinv_v * (h3[v,:] . W3) -------------------------------------
__global__ __launch_bounds__(256) void zlin_k(const float* __restrict__ H,
                                              const float* __restrict__ W3,
                                              const float* __restrict__ dinv,
                                              float* __restrict__ z) {
    int t = threadIdx.x;
    int v = blockIdx.x * 64 + (t >> 2);
    int q = t & 3;
    float p = 0.f;
#pragma unroll
    for (int k = 0; k < 2; ++k) {
        int cc = q * 2 + k;
        const float* hp = &H[((size_t)cc * NTOT + v) * 16];
        const float* wp = &W3[cc * 16];
#pragma unroll
        for (int j = 0; j < 4; ++j) {
            float4 h4 = *(const float4*)(hp + j * 4);
            float4 w4 = *(const float4*)(wp + j * 4);
            p += h4.x * w4.x + h4.y * w4.y + h4.z * w4.z + h4.w * w4.w;
        }
    }
    p += __shfl_xor(p, 1);
    p += __shfl_xor(p, 2);
    if (q == 0) z[v] = p * dinv[v];
}

// ---------------- scalar aggregation for logits --------------------------------------
__global__ __launch_bounds__(256) void sagg_k(const float* __restrict__ zl,
                                              const unsigned short* __restrict__ col16,
                                              const int* __restrict__ cnt,
                                              const float* __restrict__ b3,
                                              float* __restrict__ logits) {
    int v = blockIdx.x * 256 + threadIdx.x;
    int gbase = v & ~(NPER - 1);
    int n = cnt[v];
    float dv = rsqrtf((float)n + 1.0f);
    float acc = zl[v];
    const unsigned short* ip = col16 + v;
    int i = 0;
    for (; i + 2 <= n; i += 2) {
        int a = ip[(size_t)i * NTOT];
        int b = ip[(size_t)(i + 1) * NTOT];
        acc += zl[gbase + a] + zl[gbase + b];
    }
    for (; i < n; ++i) acc += zl[gbase + ip[(size_t)i * NTOT]];
    logits[v] = acc * dv + b3[0];
}

// ---------------- per-graph top-K threshold + mask -----------------------------------
__global__ __launch_bounds__(256) void mask_k(const float* __restrict__ logits,
                                              float* __restrict__ out) {
    __shared__ float sl[1024];
    __shared__ float rv[256];
    __shared__ int   ri[256];
    __shared__ float sth;
    int g = blockIdx.x, t = threadIdx.x;
    const float* lg = logits + (size_t)g * 1024;
#pragma unroll
    for (int i = 0; i < 4; ++i) sl[t + 256 * i] = lg[t + 256 * i];
    __syncthreads();
    for (int pass = 0; pass < KSEL; ++pass) {
        float bv = -INFINITY;
        int bi = 0;
#pragma unroll
        for (int i = 0; i < 4; ++i) {
            float v = sl[t + 256 * i];
            if (v > bv) { bv = v; bi = t + 256 * i; }
        }
        rv[t] = bv; ri[t] = bi;
        __syncthreads();
        for (int s = 128; s > 0; s >>= 1) {
            if (t < s) {
                if (rv[t + s] > rv[t]) { rv[t] = rv[t + s]; ri[t] = ri[t + s]; }
            }
            __syncthreads();
        }
        if (t == 0) { sth = rv[0]; sl[ri[0]] = -INFINITY; }
        __syncthreads();
    }
    float th = sth;
#pragma unroll
    for (int i = 0; i < 4; ++i) {
        float v = lg[t + 256 * i];
        out[(size_t)g * 1024 + t + 256 * i] = (v >= th) ? 1.f : 0.f;
    }
}

// =====================================================================================
extern "C" void kernel_launch(void* const* d_in, const int* in_sizes, int n_in,
                              void* d_out, int out_size, void* d_ws, size_t ws_size,
                              hipStream_t stream) {
    const float* x        = (const float*)d_in[0];
    const int*   edge_src = (const int*)d_in[1];
    const int*   edge_dst = (const int*)d_in[2];
    const float* W0 = (const float*)d_in[4];
    const float* b0 = (const float*)d_in[5];
    const float* W1 = (const float*)d_in[6];
    const float* b1 = (const float*)d_in[7];
    const float* Wf = (const float*)d_in[8];
    const float* bf = (const float*)d_in[9];
    const float* W2 = (const float*)d_in[10];
    const float* b2 = (const float*)d_in[11];
    const float* W3 = (const float*)d_in[12];
    const float* b3 = (const float*)d_in[13];
    float* out = (float*)d_out;

    char* w = (char*)d_ws;
    int*            cnt    = (int*)w;            w += (size_t)NTOT * 4;
    unsigned short* col16  = (unsigned short*)w; w += (size_t)NTOT * MAXDEG * 2;
    float*          dinv   = (float*)w;          w += (size_t)NTOT * 4;
    float*          fvec   = (float*)w;          w += (size_t)NTOT * 4;
    float*          P      = (float*)w;          w += (size_t)NTOT * 128 * 4;
    float*          Q      = (float*)w;          w += (size_t)NTOT * 128 * 4;
    float*          part   = (float*)w;          w += (size_t)NB * 128 * 4;
    float*          gproj  = (float*)w;          w += (size_t)NB * 128 * 4;
    float*          z      = (float*)w;          w += (size_t)NTOT * 4;
    float*          logits = (float*)w;          w += (size_t)NTOT * 4;

    hipMemsetAsync(cnt, 0, (size_t)NTOT * 4, stream);
    hipMemsetAsync(part, 0, (size_t)NB * 128 * 4, stream);   // atomicMax base (relu>=0)
    csr_k<<<ETOT / 256, 256, 0, stream>>>(edge_src, edge_dst, cnt, col16);
    dinv_k<<<NTOT / 256, 256, 0, stream>>>(cnt, dinv);
    fsum_k<<<NTOT / 256, 256, 0, stream>>>(col16, cnt, dinv, fvec);

    // conv0: ax = agg(x) [64-wide], h0 = relu(ax@W0+b0) with fused maxpool -> part
    agg_k<<<NB * 4, 1024, 0, stream>>>(nullptr, x, col16, cnt, dinv, P, 2);
    gemm_k<<<NTOT / 128, 256, 0, stream>>>(P, W0, b0, Q, FEAT, nullptr, nullptr, part);

    glob_k<<<NB, 128, 0, stream>>>(part, Wf, bf, W2, gproj);

    // conv1 twice (same weights): a = agg(h), h = relu(a@W1+b1)
    agg_k<<<NB * 8, 1024, 0, stream>>>(Q, nullptr, col16, cnt, dinv, P, 3);
    gemm_k<<<NTOT / 128, 256, 0, stream>>>(P, W1, b1, Q, HID, nullptr, nullptr, nullptr);
    agg_k<<<NB * 8, 1024, 0, stream>>>(Q, nullptr, col16, cnt, dinv, P, 3);
    gemm_k<<<NTOT / 128, 256, 0, stream>>>(P, W1, b1, Q, HID, nullptr, nullptr, nullptr);

    // conv2: a = agg(h2), h3 = relu(a@W2a + f*gproj + b2)
    agg_k<<<NB * 8, 1024, 0, stream>>>(Q, nullptr, col16, cnt, dinv, P, 3);
    gemm_k<<<NTOT / 128, 256, 0, stream>>>(P, W2, b2, Q, HID, fvec, gproj, nullptr);

    // logits = agg_scalar(h3@W3) + b3, then per-graph top-10 mask
    zlin_k<<<NTOT / 64, 256, 0, stream>>>(Q, W3, dinv, z);
    sagg_k<<<NTOT / 256, 256, 0, stream>>>(z, col16, cnt, b3, logits);
    mask_k<<<NB, 256, 0, stream>>>(logits, out);
}

// Round 7
// 374.682 us; speedup vs baseline: 1.0427x; 1.0427x over previous
//
#include <hip/hip_runtime.h>
#include <math.h>

#define NB    64        // graphs
#define NPER  1024      // nodes per graph
#define NTOT  65536     // total nodes
#define ETOT  1048576   // edges
#define FEAT  64
#define HID   128
#define KSEL  10
#define MAXDEG 64       // CSR slot capacity per node (max in-degree ~40)

// Structure (agg commuted before the weight multiply):
//   a   = agg(h)            agg_k   : LDS-staged, dinv folded into staging + epilogue
//   h'  = relu(a W + b)     gemm_k  : 128x128 tile, fused epilogue
// gemm epilogue modes: +bias/relu always; optional per-graph col-max (part),
// optional concat-glob term (fvec*gproj), optional z = dinv*(relu(...)@W3) (no dense out).
// Layouts: feature buffers chunk-major C[c][v][16]; col16 slot-major u16 local idx.

// ---------------- CSR build (slot-major, u16 local index) ----------------
__global__ __launch_bounds__(256) void csr_k(const int* __restrict__ src,
                                             const int* __restrict__ dst,
                                             int* __restrict__ cnt,
                                             unsigned short* __restrict__ col16) {
    int e = blockIdx.x * 256 + threadIdx.x;
    if (e >= ETOT) return;
    int d = dst[e];
    int s = src[e];
    int pos = atomicAdd(&cnt[d], 1);
    col16[(size_t)pos * NTOT + d] = (unsigned short)(s & (NPER - 1));
}

// ---------------- LDS-staged aggregation -------------------------------------------
// out_v = dinv_v * (dinv_v*in_v + sum_s dinv_s*in_s); block=(graph g, chunk c).
// Optional: fvec epilogue (c==0 blocks): f_v = dinv_v*(dinv_v + sum_s dinv_s).
__global__ __launch_bounds__(1024) void agg_k(const float* __restrict__ H,
                                              const float* __restrict__ x,
                                              const unsigned short* __restrict__ col16,
                                              const int* __restrict__ cnt,
                                              float* __restrict__ out,
                                              int cshift,
                                              float* __restrict__ fvec) {
    __shared__ float4 sy4[4096];   // 64 KB
    int t = threadIdx.x;
    int g = blockIdx.x >> cshift;
    int c = blockIdx.x & ((1 << cshift) - 1);
    int gbase = g << 10;

#pragma unroll
    for (int j = 0; j < 4; ++j) {
        int fl = j * 1024 + t;
        int v = fl >> 2, q = fl & 3;
        float dvv = rsqrtf((float)cnt[gbase + v] + 1.0f);
        float4 z;
        if (x) z = *(const float4*)&x[(size_t)(gbase + v) * FEAT + c * 16 + q * 4];
        else   z = *(const float4*)&H[((size_t)c * NTOT + gbase + v) * 16 + q * 4];
        z.x *= dvv; z.y *= dvv; z.z *= dvv; z.w *= dvv;
        sy4[fl] = z;
    }
    __syncthreads();

    int f4 = t & 3;
    int vl = t >> 2;                        // 0..255

#pragma unroll 1
    for (int pass = 0; pass < 4; ++pass) {
        int v = pass * 256 + vl;
        int gv = gbase + v;
        int n = cnt[gv];
        float dv = rsqrtf((float)n + 1.0f);
        const unsigned short* ip = col16 + gv;
        float4 acc = sy4[v * 4 + f4];       // self term (already dinv-scaled)
        int i = 0;
        for (; i + 2 <= n; i += 2) {
            int a = ip[(size_t)i * NTOT];
            int b = ip[(size_t)(i + 1) * NTOT];
            float4 ya = sy4[a * 4 + f4];
            float4 yb = sy4[b * 4 + f4];
            acc.x += ya.x + yb.x;
            acc.y += ya.y + yb.y;
            acc.z += ya.z + yb.z;
            acc.w += ya.w + yb.w;
        }
        if (i < n) {
            float4 ya = sy4[(int)ip[(size_t)i * NTOT] * 4 + f4];
            acc.x += ya.x; acc.y += ya.y; acc.z += ya.z; acc.w += ya.w;
        }
        acc.x *= dv; acc.y *= dv; acc.z *= dv; acc.w *= dv;
        *(float4*)&out[((size_t)c * NTOT + gv) * 16 + f4 * 4] = acc;
    }

    if (fvec && c == 0) {   // f_v = dinv_v*(dinv_v + sum dinv_s), reuse sy4 as scalar buf
        __syncthreads();
        float* sdv = (float*)sy4;
        float dv = rsqrtf((float)cnt[gbase + t] + 1.0f);
        sdv[t] = dv;
        __syncthreads();
        int n = cnt[gbase + t];
        float acc = dv;
        const unsigned short* ip = col16 + gbase + t;
        for (int i = 0; i < n; ++i) acc += sdv[ip[(size_t)i * NTOT]];
        fvec[gbase + t] = dv * acc;
    }
}

// ---------------- fp32 GEMM 128x128 tile, 8x8 micro-tile, fused epilogue ----------
__global__ __launch_bounds__(256, 4) void gemm_k(const float* __restrict__ A,
                                                 const float* __restrict__ W,
                                                 const float* __restrict__ bias,
                                                 float* __restrict__ out,
                                                 int K,
                                                 const float* __restrict__ fvec,
                                                 const float* __restrict__ gproj,
                                                 float* __restrict__ part,
                                                 const float* __restrict__ W3,
                                                 const int* __restrict__ cnt,
                                                 float* __restrict__ zout) {
    __shared__ float At[32][140];   // [k][row]
    __shared__ float Wt[32][128];   // [k][col]
    int t = threadIdx.x;
    int row0 = blockIdx.x * 128;
    int tx = t & 15;                // col group: cols tx*8..+7
    int ty = t >> 4;                // row group: rows ty*8..+7

    float acc[8][8];
#pragma unroll
    for (int i = 0; i < 8; ++i)
#pragma unroll
        for (int j = 0; j < 8; ++j) acc[i][j] = 0.f;

    for (int kt = 0; kt < K; kt += 32) {
        {   // stage A (chunk-major): 2 chunks x 128 rows x 16 k, transposed
            int q = t & 3, r0 = t >> 2;     // r0: 0..63
#pragma unroll
            for (int half = 0; half < 2; ++half) {
                int cc = (kt >> 4) + half;
#pragma unroll
                for (int p = 0; p < 2; ++p) {
                    int r = r0 + p * 64;
                    float4 v4 = *(const float4*)&A[((size_t)cc * NTOT + row0 + r) * 16 + q * 4];
                    At[half * 16 + q * 4 + 0][r] = v4.x;
                    At[half * 16 + q * 4 + 1][r] = v4.y;
                    At[half * 16 + q * 4 + 2][r] = v4.z;
                    At[half * 16 + q * 4 + 3][r] = v4.w;
                }
            }
        }
        {   // stage W: 32 k x 128 cols
            int c4 = (t & 31) * 4, kr = t >> 5;
#pragma unroll
            for (int p = 0; p < 4; ++p) {
                int k = kr + p * 8;
                *(float4*)&Wt[k][c4] = *(const float4*)&W[(size_t)(kt + k) * 128 + c4];
            }
        }
        __syncthreads();
#pragma unroll
        for (int k = 0; k < 32; ++k) {
            float4 a0 = *(const float4*)&At[k][ty * 8];
            float4 a1 = *(const float4*)&At[k][ty * 8 + 4];
            float4 w0 = *(const float4*)&Wt[k][tx * 8];
            float4 w1 = *(const float4*)&Wt[k][tx * 8 + 4];
            float a[8] = {a0.x, a0.y, a0.z, a0.w, a1.x, a1.y, a1.z, a1.w};
            float w[8] = {w0.x, w0.y, w0.z, w0.w, w1.x, w1.y, w1.z, w1.w};
#pragma unroll
            for (int i = 0; i < 8; ++i)
#pragma unroll
                for (int j = 0; j < 8; ++j) acc[i][j] += a[i] * w[j];
        }
        __syncthreads();
    }

    int g = row0 >> 10;
    float b[8];
#pragma unroll
    for (int j = 0; j < 8; ++j) b[j] = bias[tx * 8 + j];
    float gp[8], fr[8];
    if (fvec) {
#pragma unroll
        for (int j = 0; j < 8; ++j) gp[j] = gproj[(size_t)g * 128 + tx * 8 + j];
#pragma unroll
        for (int i = 0; i < 8; ++i) fr[i] = fvec[row0 + ty * 8 + i];
    }
    float w3[8];
    if (zout) {
#pragma unroll
        for (int j = 0; j < 8; ++j) w3[j] = W3[tx * 8 + j];
    }
    float m[8];
#pragma unroll
    for (int j = 0; j < 8; ++j) m[j] = 0.f;   // relu floor
    float zp[8];

    int cc = tx >> 1, off = (tx & 1) * 8;
#pragma unroll
    for (int i = 0; i < 8; ++i) {
        int r = row0 + ty * 8 + i;
        float o[8];
        float zpi = 0.f;
#pragma unroll
        for (int j = 0; j < 8; ++j) {
            float v = acc[i][j] + b[j];
            if (fvec) v += fr[i] * gp[j];
            v = fmaxf(v, 0.f);
            o[j] = v;
            if (part) m[j] = fmaxf(m[j], v);
            if (zout) zpi += v * w3[j];
        }
        zp[i] = zpi;
        if (out) {
            float* op = &out[((size_t)cc * NTOT + r) * 16 + off];
            *(float4*)op       = make_float4(o[0], o[1], o[2], o[3]);
            *(float4*)(op + 4) = make_float4(o[4], o[5], o[6], o[7]);
        }
    }

    if (zout) {   // reduce partial dots across 16 col-groups -> z[row] = dot * dinv
        float* zsm = &At[0][0];   // 128 x 16 floats
        __syncthreads();
#pragma unroll
        for (int i = 0; i < 8; ++i) zsm[(ty * 8 + i) * 16 + tx] = zp[i];
        __syncthreads();
        if (t < 128) {
            float s = 0.f;
#pragma unroll
            for (int xg = 0; xg < 16; ++xg) s += zsm[t * 16 + xg];
            zout[row0 + t] = s * rsqrtf((float)cnt[row0 + t] + 1.0f);
        }
    }

    if (part) {   // per-graph col-max: reduce across 16 row-groups, then atomicMax
        float* sm = &At[0][0];
        __syncthreads();
#pragma unroll
        for (int j = 0; j < 8; ++j) sm[ty * 128 + tx * 8 + j] = m[j];
        __syncthreads();
        for (int s = 8; s >= 1; s >>= 1) {
            if (ty < s) {
#pragma unroll
                for (int j = 0; j < 8; ++j) {
                    int idx = ty * 128 + tx * 8 + j;
                    sm[idx] = fmaxf(sm[idx], sm[(ty + s) * 128 + tx * 8 + j]);
                }
            }
            __syncthreads();
        }
        if (ty == 0) {
            int* pp = (int*)&part[(size_t)g * 128 + tx * 8];
#pragma unroll
            for (int j = 0; j < 8; ++j) atomicMax(pp + j, __float_as_int(sm[tx * 8 + j]));
        }
    }
}

// ---------------- glob = maxpool@Wf + bf ; gproj = glob @ W2[128:256,:] --------------
__global__ __launch_bounds__(128) void glob_k(const float* __restrict__ part,
                                              const float* __restrict__ Wf,
                                              const float* __restrict__ bf,
                                              const float* __restrict__ W2,
                                              float* __restrict__ gproj) {
    __shared__ float mp[128];
    __shared__ float gl[128];
    int g = blockIdx.x, t = threadIdx.x;
    mp[t] = part[(size_t)g * 128 + t];
    __syncthreads();
    float acc = bf[t];
    for (int k = 0; k < 128; ++k) acc += mp[k] * Wf[(size_t)k * 128 + t];
    gl[t] = acc;
    __syncthreads();
    float acc2 = 0.f;
    for (int k = 0; k < 128; ++k) acc2 += gl[k] * W2[(size_t)(128 + k) * 128 + t];
    gproj[(size_t)g * 128 + t] = acc2;
}

// ---------------- fused scalar-agg + top-K mask (one block per graph) ----------------
__global__ __launch_bounds__(256) void smask_k(const float* __restrict__ z,
                                               const unsigned short* __restrict__ col16,
                                               const int* __restrict__ cnt,
                                               const float* __restrict__ b3,
                                               float* __restrict__ out) {
    __shared__ float sz[1024];
    __shared__ float sl[1024];
    __shared__ float slo[1024];
    __shared__ float rv[256];
    __shared__ int   ri[256];
    __shared__ float sth;
    int g = blockIdx.x, t = threadIdx.x;
    int base = g << 10;
#pragma unroll
    for (int i = 0; i < 4; ++i) sz[t + 256 * i] = z[base + t + 256 * i];
    __syncthreads();
    float bb = b3[0];
#pragma unroll 1
    for (int i = 0; i < 4; ++i) {
        int v = t + 256 * i;
        int gv = base + v;
        int n = cnt[gv];
        float dv = rsqrtf((float)n + 1.0f);
        float acc = sz[v];
        const unsigned short* ip = col16 + gv;
        int j = 0;
        for (; j + 2 <= n; j += 2)
            acc += sz[ip[(size_t)j * NTOT]] + sz[ip[(size_t)(j + 1) * NTOT]];
        for (; j < n; ++j) acc += sz[ip[(size_t)j * NTOT]];
        float lg = acc * dv + bb;
        sl[v] = lg; slo[v] = lg;
    }
    __syncthreads();
    for (int pass = 0; pass < KSEL; ++pass) {
        float bv = -INFINITY;
        int bi = 0;
#pragma unroll
        for (int i = 0; i < 4; ++i) {
            float v = sl[t + 256 * i];
            if (v > bv) { bv = v; bi = t + 256 * i; }
        }
        rv[t] = bv; ri[t] = bi;
        __syncthreads();
        for (int s = 128; s > 0; s >>= 1) {
            if (t < s) {
                if (rv[t + s] > rv[t]) { rv[t] = rv[t + s]; ri[t] = ri[t + s]; }
            }
            __syncthreads();
        }
        if (t == 0) { sth = rv[0]; sl[ri[0]] = -INFINITY; }
        __syncthreads();
    }
    float th = sth;
#pragma unroll
    for (int i = 0; i < 4; ++i) {
        int v = t + 256 * i;
        out[base + v] = (slo[v] >= th) ? 1.f : 0.f;
    }
}

// =====================================================================================
extern "C" void kernel_launch(void* const* d_in, const int* in_sizes, int n_in,
                              void* d_out, int out_size, void* d_ws, size_t ws_size,
                              hipStream_t stream) {
    const float* x        = (const float*)d_in[0];
    const int*   edge_src = (const int*)d_in[1];
    const int*   edge_dst = (const int*)d_in[2];
    const float* W0 = (const float*)d_in[4];
    const float* b0 = (const float*)d_in[5];
    const float* W1 = (const float*)d_in[6];
    const float* b1 = (const float*)d_in[7];
    const float* Wf = (const float*)d_in[8];
    const float* bf = (const float*)d_in[9];
    const float* W2 = (const float*)d_in[10];
    const float* b2 = (const float*)d_in[11];
    const float* W3 = (const float*)d_in[12];
    const float* b3 = (const float*)d_in[13];
    float* out = (float*)d_out;

    char* w = (char*)d_ws;
    int*            cnt    = (int*)w;            w += (size_t)NTOT * 4;
    unsigned short* col16  = (unsigned short*)w; w += (size_t)NTOT * MAXDEG * 2;
    float*          fvec   = (float*)w;          w += (size_t)NTOT * 4;
    float*          P      = (float*)w;          w += (size_t)NTOT * 128 * 4;
    float*          Q      = (float*)w;          w += (size_t)NTOT * 128 * 4;
    float*          part   = (float*)w;          w += (size_t)NB * 128 * 4;
    float*          gproj  = (float*)w;          w += (size_t)NB * 128 * 4;
    float*          z      = (float*)w;          w += (size_t)NTOT * 4;

    hipMemsetAsync(cnt, 0, (size_t)NTOT * 4, stream);
    hipMemsetAsync(part, 0, (size_t)NB * 128 * 4, stream);   // atomicMax base (relu>=0)
    csr_k<<<ETOT / 256, 256, 0, stream>>>(edge_src, edge_dst, cnt, col16);

    // conv0: ax = agg(x) [64-wide]; h0 = relu(ax@W0+b0), fused maxpool -> part
    agg_k<<<NB * 4, 1024, 0, stream>>>(nullptr, x, col16, cnt, P, 2, nullptr);
    gemm_k<<<NTOT / 128, 256, 0, stream>>>(P, W0, b0, Q, FEAT, nullptr, nullptr, part,
                                           nullptr, cnt, nullptr);

    glob_k<<<NB, 128, 0, stream>>>(part, Wf, bf, W2, gproj);

    // conv1 twice (same weights)
    agg_k<<<NB * 8, 1024, 0, stream>>>(Q, nullptr, col16, cnt, P, 3, nullptr);
    gemm_k<<<NTOT / 128, 256, 0, stream>>>(P, W1, b1, Q, HID, nullptr, nullptr, nullptr,
                                           nullptr, cnt, nullptr);
    agg_k<<<NB * 8, 1024, 0, stream>>>(Q, nullptr, col16, cnt, P, 3, nullptr);
    gemm_k<<<NTOT / 128, 256, 0, stream>>>(P, W1, b1, Q, HID, nullptr, nullptr, nullptr,
                                           nullptr, cnt, nullptr);

    // conv2: a = agg(h2) (+fvec epilogue); z = dinv*(relu(a@W2a + f*gproj + b2)@W3)
    agg_k<<<NB * 8, 1024, 0, stream>>>(Q, nullptr, col16, cnt, P, 3, fvec);
    gemm_k<<<NTOT / 128, 256, 0, stream>>>(P, W2, b2, nullptr, HID, fvec, gproj, nullptr,
                                           W3, cnt, z);

    // logits = agg_scalar(z) + b3, then per-graph top-10 mask (fused)
    smask_k<<<NB, 256, 0, stream>>>(z, col16, cnt, b3, out);
}

// Round 8
// 357.594 us; speedup vs baseline: 1.0925x; 1.0478x over previous
//
#include <hip/hip_runtime.h>
#include <math.h>

#define NB    64        // graphs
#define NPER  1024      // nodes per graph
#define NTOT  65536     // total nodes
#define ETOT  1048576   // edges
#define FEAT  64
#define HID   128
#define KSEL  10
#define MAXDEG 64       // CSR slot capacity per node (max in-degree ~40)

// Pipeline (agg commuted before the weight multiply, dinv folded into gemm output):
//   AT = agg(Z)            agg_k  : LDS-staged gather; output FEATURE-MAJOR AT[k][v]
//   Z' = relu(AT@W+b)*dinv gemm_k : 64x128 tile; A-stage = straight b128 copy
// gemm epilogue options: per-graph col-max (part), concat-glob (fvec*gproj),
// z = dinv*(relu(.)@W3) with no dense output (conv2).
// Layouts: Z chunk-major C[c][v][16]; AT feature-major [k][v]; col16 slot-major u16.

// ---------------- CSR build (slot-major, u16 local index) ----------------
__global__ __launch_bounds__(256) void csr_k(const int* __restrict__ src,
                                             const int* __restrict__ dst,
                                             int* __restrict__ cnt,
                                             unsigned short* __restrict__ col16) {
    int e = blockIdx.x * 256 + threadIdx.x;
    if (e >= ETOT) return;
    int d = dst[e];
    int s = src[e];
    int pos = atomicAdd(&cnt[d], 1);
    col16[(size_t)pos * NTOT + d] = (unsigned short)(s & (NPER - 1));
}

// ---------------- LDS-staged aggregation -> feature-major output -------------------
// block=(graph g, chunk c). Z input is pre-scaled by dinv (gemm did it); x input
// (conv0) scaled here. out_v = dv * sum(staged over {v} u N(v)).
__global__ __launch_bounds__(1024) void agg_k(const float* __restrict__ Z,
                                              const float* __restrict__ x,
                                              const unsigned short* __restrict__ col16,
                                              const int* __restrict__ cnt,
                                              float* __restrict__ outAT,
                                              int cshift,
                                              float* __restrict__ fvec) {
    __shared__ float4 sy4[4096];   // 64 KB
    int t = threadIdx.x;
    int g = blockIdx.x >> cshift;
    int c = blockIdx.x & ((1 << cshift) - 1);
    int gbase = g << 10;

    if (x) {
#pragma unroll
        for (int j = 0; j < 4; ++j) {
            int fl = j * 1024 + t;
            int v = fl >> 2, q = fl & 3;
            float dvv = rsqrtf((float)cnt[gbase + v] + 1.0f);
            float4 z = *(const float4*)&x[(size_t)(gbase + v) * FEAT + c * 16 + q * 4];
            z.x *= dvv; z.y *= dvv; z.z *= dvv; z.w *= dvv;
            sy4[fl] = z;
        }
    } else {
        const float4* Zg4 = (const float4*)(Z + ((size_t)c * NTOT + gbase) * 16);
#pragma unroll
        for (int j = 0; j < 4; ++j) sy4[j * 1024 + t] = Zg4[j * 1024 + t];
    }
    __syncthreads();

    int f4 = t & 3;
    int vl = t >> 2;                        // 0..255

#pragma unroll 1
    for (int pass = 0; pass < 4; ++pass) {
        int v = pass * 256 + vl;
        int gv = gbase + v;
        int n = cnt[gv];
        float dv = rsqrtf((float)n + 1.0f);
        const unsigned short* ip = col16 + gv;
        float4 acc = sy4[v * 4 + f4];       // self term
        int i = 0;
        for (; i + 2 <= n; i += 2) {
            int a = ip[(size_t)i * NTOT];
            int b = ip[(size_t)(i + 1) * NTOT];
            float4 ya = sy4[a * 4 + f4];
            float4 yb = sy4[b * 4 + f4];
            acc.x += ya.x + yb.x;
            acc.y += ya.y + yb.y;
            acc.z += ya.z + yb.z;
            acc.w += ya.w + yb.w;
        }
        if (i < n) {
            float4 ya = sy4[(int)ip[(size_t)i * NTOT] * 4 + f4];
            acc.x += ya.x; acc.y += ya.y; acc.z += ya.z; acc.w += ya.w;
        }
        acc.x *= dv; acc.y *= dv; acc.z *= dv; acc.w *= dv;
        int krow = c * 16 + f4 * 4;         // feature-major write: 4 rows, col gv
        outAT[(size_t)(krow + 0) * NTOT + gv] = acc.x;
        outAT[(size_t)(krow + 1) * NTOT + gv] = acc.y;
        outAT[(size_t)(krow + 2) * NTOT + gv] = acc.z;
        outAT[(size_t)(krow + 3) * NTOT + gv] = acc.w;
    }

    if (fvec && c == 0) {   // f_v = dinv_v*(dinv_v + sum dinv_s)
        __syncthreads();
        float* sdv = (float*)sy4;
        float dv = rsqrtf((float)cnt[gbase + t] + 1.0f);
        sdv[t] = dv;
        __syncthreads();
        int n = cnt[gbase + t];
        float acc = dv;
        const unsigned short* ip = col16 + gbase + t;
        for (int i = 0; i < n; ++i) acc += sdv[ip[(size_t)i * NTOT]];
        fvec[gbase + t] = dv * acc;
    }
}

// ---------------- fp32 GEMM 64x128 tile, 8x4 micro-tile, fused epilogue -----------
__global__ __launch_bounds__(256, 4) void gemm_k(const float* __restrict__ AT,
                                                 const float* __restrict__ W,
                                                 const float* __restrict__ bias,
                                                 float* __restrict__ outZ,
                                                 int K,
                                                 const float* __restrict__ fvec,
                                                 const float* __restrict__ gproj,
                                                 float* __restrict__ part,
                                                 const float* __restrict__ W3,
                                                 const int* __restrict__ cnt,
                                                 float* __restrict__ zout) {
    __shared__ float At[32][68];    // [k][row]
    __shared__ float Wt[32][132];   // [k][col]
    int t = threadIdx.x;
    int row0 = blockIdx.x * 64;
    int tx = t & 31;                // col group: cols tx*4..+3
    int ty = t >> 5;                // row group: rows ty*8..+7

    float acc[8][4];
#pragma unroll
    for (int i = 0; i < 8; ++i)
#pragma unroll
        for (int j = 0; j < 4; ++j) acc[i][j] = 0.f;

    for (int kt = 0; kt < K; kt += 32) {
        {   // stage A: straight b128 copy from feature-major AT
            int r4 = (t & 15) * 4, k2 = t >> 4;   // k2: 0..15
#pragma unroll
            for (int p = 0; p < 2; ++p) {
                int k = k2 + p * 16;
                float4 v4 = *(const float4*)&AT[(size_t)(kt + k) * NTOT + row0 + r4];
                *(float4*)&At[k][r4] = v4;
            }
        }
        {   // stage W: 32 k x 128 cols
            int c4 = (t & 31) * 4, kr = t >> 5;
#pragma unroll
            for (int p = 0; p < 4; ++p) {
                int k = kr + p * 8;
                *(float4*)&Wt[k][c4] = *(const float4*)&W[(size_t)(kt + k) * 128 + c4];
            }
        }
        __syncthreads();
#pragma unroll
        for (int k = 0; k < 32; ++k) {
            float4 a0 = *(const float4*)&At[k][ty * 8];
            float4 a1 = *(const float4*)&At[k][ty * 8 + 4];
            float4 w  = *(const float4*)&Wt[k][tx * 4];
            float a[8] = {a0.x, a0.y, a0.z, a0.w, a1.x, a1.y, a1.z, a1.w};
#pragma unroll
            for (int i = 0; i < 8; ++i) {
                acc[i][0] += a[i] * w.x;
                acc[i][1] += a[i] * w.y;
                acc[i][2] += a[i] * w.z;
                acc[i][3] += a[i] * w.w;
            }
        }
        __syncthreads();
    }

    int g = row0 >> 10;
    float b[4];
#pragma unroll
    for (int j = 0; j < 4; ++j) b[j] = bias[tx * 4 + j];
    float gp[4], fr[8];
    if (fvec) {
#pragma unroll
        for (int j = 0; j < 4; ++j) gp[j] = gproj[(size_t)g * 128 + tx * 4 + j];
#pragma unroll
        for (int i = 0; i < 8; ++i) fr[i] = fvec[row0 + ty * 8 + i];
    }
    float w3[4];
    if (zout) {
#pragma unroll
        for (int j = 0; j < 4; ++j) w3[j] = W3[tx * 4 + j];
    }
    float dvs[8];
#pragma unroll
    for (int i = 0; i < 8; ++i) dvs[i] = rsqrtf((float)cnt[row0 + ty * 8 + i] + 1.0f);
    float m[4];
#pragma unroll
    for (int j = 0; j < 4; ++j) m[j] = 0.f;   // relu floor
    float zp[8];

    int cc = tx >> 2, off = (tx & 3) * 4;
#pragma unroll
    for (int i = 0; i < 8; ++i) {
        int r = row0 + ty * 8 + i;
        float o[4];
        float zpi = 0.f;
#pragma unroll
        for (int j = 0; j < 4; ++j) {
            float v = acc[i][j] + b[j];
            if (fvec) v += fr[i] * gp[j];
            v = fmaxf(v, 0.f);
            if (part) m[j] = fmaxf(m[j], v);
            if (zout) zpi += v * w3[j];
            o[j] = v * dvs[i];              // fold dinv into output
        }
        zp[i] = zpi;
        if (outZ)
            *(float4*)&outZ[((size_t)cc * NTOT + r) * 16 + off] =
                make_float4(o[0], o[1], o[2], o[3]);
    }

    if (zout) {   // reduce partial dots across 32 col-groups -> z[row]
        float* zsm = &At[0][0];   // 64 rows x 32 = 2048 floats
        __syncthreads();
#pragma unroll
        for (int i = 0; i < 8; ++i) zsm[(ty * 8 + i) * 32 + tx] = zp[i];
        __syncthreads();
        if (t < 64) {
            float s = 0.f;
#pragma unroll
            for (int xg = 0; xg < 32; ++xg) s += zsm[t * 32 + xg];
            zout[row0 + t] = s * rsqrtf((float)cnt[row0 + t] + 1.0f);
        }
    }

    if (part) {   // per-graph col-max: reduce across 8 row-groups, then atomicMax
        float* sm = &At[0][0];    // 8 x 128 floats
        __syncthreads();
#pragma unroll
        for (int j = 0; j < 4; ++j) sm[ty * 128 + tx * 4 + j] = m[j];
        __syncthreads();
        for (int s = 4; s >= 1; s >>= 1) {
            if (ty < s) {
#pragma unroll
                for (int j = 0; j < 4; ++j) {
                    int idx = ty * 128 + tx * 4 + j;
                    sm[idx] = fmaxf(sm[idx], sm[(ty + s) * 128 + tx * 4 + j]);
                }
            }
            __syncthreads();
        }
        if (ty == 0) {
            int* pp = (int*)&part[(size_t)g * 128 + tx * 4];
#pragma unroll
            for (int j = 0; j < 4; ++j) atomicMax(pp + j, __float_as_int(sm[tx * 4 + j]));
        }
    }
}

// ---------------- glob = maxpool@Wf + bf ; gproj = glob @ W2[128:256,:] --------------
__global__ __launch_bounds__(128) void glob_k(const float* __restrict__ part,
                                              const float* __restrict__ Wf,
                                              const float* __restrict__ bf,
                                              const float* __restrict__ W2,
                                              float* __restrict__ gproj) {
    __shared__ float mp[128];
    __shared__ float gl[128];
    int g = blockIdx.x, t = threadIdx.x;
    mp[t] = part[(size_t)g * 128 + t];
    __syncthreads();
    float acc = bf[t];
    for (int k = 0; k < 128; ++k) acc += mp[k] * Wf[(size_t)k * 128 + t];
    gl[t] = acc;
    __syncthreads();
    float acc2 = 0.f;
    for (int k = 0; k < 128; ++k) acc2 += gl[k] * W2[(size_t)(128 + k) * 128 + t];
    gproj[(size_t)g * 128 + t] = acc2;
}

// ---------------- fused scalar-agg + top-K mask (one block per graph) ----------------
__global__ __launch_bounds__(256) void smask_k(const float* __restrict__ z,
                                               const unsigned short* __restrict__ col16,
                                               const int* __restrict__ cnt,
                                               const float* __restrict__ b3,
                                               float* __restrict__ out) {
    __shared__ float sz[1024];
    __shared__ float sl[1024];
    __shared__ float slo[1024];
    __shared__ float rv[256];
    __shared__ int   ri[256];
    __shared__ float sth;
    int g = blockIdx.x, t = threadIdx.x;
    int base = g << 10;
#pragma unroll
    for (int i = 0; i < 4; ++i) sz[t + 256 * i] = z[base + t + 256 * i];
    __syncthreads();
    float bb = b3[0];
#pragma unroll 1
    for (int i = 0; i < 4; ++i) {
        int v = t + 256 * i;
        int gv = base + v;
        int n = cnt[gv];
        float dv = rsqrtf((float)n + 1.0f);
        float acc = sz[v];
        const unsigned short* ip = col16 + gv;
        int j = 0;
        for (; j + 2 <= n; j += 2)
            acc += sz[ip[(size_t)j * NTOT]] + sz[ip[(size_t)(j + 1) * NTOT]];
        for (; j < n; ++j) acc += sz[ip[(size_t)j * NTOT]];
        float lg = acc * dv + bb;
        sl[v] = lg; slo[v] = lg;
    }
    __syncthreads();
    for (int pass = 0; pass < KSEL; ++pass) {
        float bv = -INFINITY;
        int bi = 0;
#pragma unroll
        for (int i = 0; i < 4; ++i) {
            float v = sl[t + 256 * i];
            if (v > bv) { bv = v; bi = t + 256 * i; }
        }
        rv[t] = bv; ri[t] = bi;
        __syncthreads();
        for (int s = 128; s > 0; s >>= 1) {
            if (t < s) {
                if (rv[t + s] > rv[t]) { rv[t] = rv[t + s]; ri[t] = ri[t + s]; }
            }
            __syncthreads();
        }
        if (t == 0) { sth = rv[0]; sl[ri[0]] = -INFINITY; }
        __syncthreads();
    }
    float th = sth;
#pragma unroll
    for (int i = 0; i < 4; ++i) {
        int v = t + 256 * i;
        out[base + v] = (slo[v] >= th) ? 1.f : 0.f;
    }
}

// =====================================================================================
extern "C" void kernel_launch(void* const* d_in, const int* in_sizes, int n_in,
                              void* d_out, int out_size, void* d_ws, size_t ws_size,
                              hipStream_t stream) {
    const float* x        = (const float*)d_in[0];
    const int*   edge_src = (const int*)d_in[1];
    const int*   edge_dst = (const int*)d_in[2];
    const float* W0 = (const float*)d_in[4];
    const float* b0 = (const float*)d_in[5];
    const float* W1 = (const float*)d_in[6];
    const float* b1 = (const float*)d_in[7];
    const float* Wf = (const float*)d_in[8];
    const float* bf = (const float*)d_in[9];
    const float* W2 = (const float*)d_in[10];
    const float* b2 = (const float*)d_in[11];
    const float* W3 = (const float*)d_in[12];
    const float* b3 = (const float*)d_in[13];
    float* out = (float*)d_out;

    char* w = (char*)d_ws;
    int*            cnt    = (int*)w;            w += (size_t)NTOT * 4;
    unsigned short* col16  = (unsigned short*)w; w += (size_t)NTOT * MAXDEG * 2;
    float*          fvec   = (float*)w;          w += (size_t)NTOT * 4;
    float*          P      = (float*)w;          w += (size_t)NTOT * 128 * 4;  // AT
    float*          Q      = (float*)w;          w += (size_t)NTOT * 128 * 4;  // Z
    float*          part   = (float*)w;          w += (size_t)NB * 128 * 4;
    float*          gproj  = (float*)w;          w += (size_t)NB * 128 * 4;
    float*          z      = (float*)w;          w += (size_t)NTOT * 4;

    hipMemsetAsync(cnt, 0, (size_t)NTOT * 4, stream);
    hipMemsetAsync(part, 0, (size_t)NB * 128 * 4, stream);   // atomicMax base (relu>=0)
    csr_k<<<ETOT / 256, 256, 0, stream>>>(edge_src, edge_dst, cnt, col16);

    // conv0: AT0 = agg(x) [64 rows]; Z0 = relu(AT0@W0+b0)*dinv, fused maxpool -> part
    agg_k<<<NB * 4, 1024, 0, stream>>>(nullptr, x, col16, cnt, P, 2, nullptr);
    gemm_k<<<NTOT / 64, 256, 0, stream>>>(P, W0, b0, Q, FEAT, nullptr, nullptr, part,
                                          nullptr, cnt, nullptr);

    glob_k<<<NB, 128, 0, stream>>>(part, Wf, bf, W2, gproj);

    // conv1 twice (same weights)
    agg_k<<<NB * 8, 1024, 0, stream>>>(Q, nullptr, col16, cnt, P, 3, nullptr);
    gemm_k<<<NTOT / 64, 256, 0, stream>>>(P, W1, b1, Q, HID, nullptr, nullptr, nullptr,
                                          nullptr, cnt, nullptr);
    agg_k<<<NB * 8, 1024, 0, stream>>>(Q, nullptr, col16, cnt, P, 3, nullptr);
    gemm_k<<<NTOT / 64, 256, 0, stream>>>(P, W1, b1, Q, HID, nullptr, nullptr, nullptr,
                                          nullptr, cnt, nullptr);

    // conv2: AT = agg(Z2) (+fvec); z = dinv*(relu(AT@W2a + f*gproj + b2)@W3)
    agg_k<<<NB * 8, 1024, 0, stream>>>(Q, nullptr, col16, cnt, P, 3, fvec);
    gemm_k<<<NTOT / 64, 256, 0, stream>>>(P, W2, b2, nullptr, HID, fvec, gproj, nullptr,
                                          W3, cnt, z);

    // logits = agg_scalar(z) + b3, then per-graph top-10 mask (fused)
    smask_k<<<NB, 256, 0, stream>>>(z, col16, cnt, b3, out);
}